// Round 1
// baseline (2153.138 us; speedup 1.0000x reference)
//
#include <hip/hip_runtime.h>
#include <math.h>

#define NSEG 440
#define CF   2112
#define HW   65536
#define NH   1024

// ---------------- ws layout (floats) ----------------
// hist : 0        (440*3 = 1320)
// feat : 2048     (440*2112 = 929280)
// h1   : 931328   (440*1024 = 450560)
// h2   : 1381888  (440*1024 = 450560)
// aff  : 1832448  (440*440  = 193600)
// invn : 2026048  (440)
// lab  : 2026488  (440 ints)
#define OFF_HIST 0
#define OFF_FEAT 2048
#define OFF_H1   931328
#define OFF_H2   1381888
#define OFF_AFF  1832448
#define OFF_INVN 2026048
#define OFF_LAB  2026488

// ---------------- histogram of y per segment (also gives counts) -------------
__global__ __launch_bounds__(256) void hist_kernel(const int* __restrict__ sp,
                                                   const int* __restrict__ y,
                                                   float* __restrict__ hist) {
    __shared__ float lh[NSEG * 3];
    int t = threadIdx.x;
    for (int i = t; i < NSEG * 3; i += 256) lh[i] = 0.0f;
    __syncthreads();
    int idx = blockIdx.x * 256 + t;
    for (int p = idx; p < HW; p += 64 * 256) {
        int s  = sp[p];
        int yy = y[p];
        unsafeAtomicAdd(&lh[s * 3 + yy], 1.0f);   // native ds_add_f32
    }
    __syncthreads();
    for (int i = t; i < NSEG * 3; i += 256)
        if (lh[i] != 0.0f) unsafeAtomicAdd(&hist[i], lh[i]);   // native global f32 add
}

// ---------------- per-channel segment sum -> feat (divided by count) ---------
__global__ __launch_bounds__(256) void segsum_kernel(const float* __restrict__ fm,
                                                     const int* __restrict__ sp,
                                                     const float* __restrict__ hist,
                                                     float* __restrict__ feat) {
    __shared__ float seg[NSEG];
    int t = threadIdx.x;
    int c = blockIdx.x;
    for (int s = t; s < NSEG; s += 256) seg[s] = 0.0f;
    __syncthreads();
    const float* f = fm + (size_t)c * HW;
    for (int it = 0; it < 64; ++it) {
        int p = it * 1024 + t * 4;
        float4 v = *(const float4*)(f + p);
        int4  si = *(const int4*)(sp + p);
        unsafeAtomicAdd(&seg[si.x], v.x);   // native ds_add_f32 (was CAS loop)
        unsafeAtomicAdd(&seg[si.y], v.y);
        unsafeAtomicAdd(&seg[si.z], v.z);
        unsafeAtomicAdd(&seg[si.w], v.w);
    }
    __syncthreads();
    for (int s = t; s < NSEG; s += 256) {
        float cnt = hist[3 * s] + hist[3 * s + 1] + hist[3 * s + 2];
        feat[(size_t)s * CF + c] = seg[s] / fmaxf(cnt, 1.0f);
    }
}

// ---------------- labels from histogram (argmax, first-max ties) -------------
__global__ void lab_kernel(const float* __restrict__ hist, int* __restrict__ lab) {
    int s = blockIdx.x * 256 + threadIdx.x;
    if (s >= NSEG) return;
    float h0 = hist[3 * s], h1 = hist[3 * s + 1], h2 = hist[3 * s + 2];
    int l = 0; float b = h0;
    if (h1 > b) { l = 1; b = h1; }
    if (h2 > b) { l = 2; b = h2; }
    if (l == 0) l = (h2 > h1) ? 2 : ((h1 > h2) ? 1 : 0);
    lab[s] = l;
}

// ---------------- split-K fp32 GEMM, 128x128 tile, BK=32, 8x8/thread ---------
// C (pre-zeroed) += A(MxK) @ B(KxN)      [TRANSB=0: B row-major KxN, ldb=N]
// C (pre-zeroed) += A(MxK) @ B^T         [TRANSB=1: B row-major NxK, ldb=K-stride]
// grid = (ceil(N/128), ceil(M/128), S); block z handles K-steps z, z+S, ...
// K must be a multiple of 32. Partials accumulated with native f32 atomics.
template <int TRANSB>
__global__ __launch_bounds__(256) void gemm_splitk(const float* __restrict__ A,
                                                   const float* __restrict__ B,
                                                   float* __restrict__ C,
                                                   int M, int N, int K,
                                                   int ldb, int ldc) {
    __shared__ __align__(16) float As[32][132];   // [kk][m], padded stride
    __shared__ __align__(16) float Bs[32][132];   // [kk][n]
    int t  = threadIdx.x;
    int n0 = blockIdx.x * 128;
    int m0 = blockIdx.y * 128;
    int S  = gridDim.z;
    int ty = t >> 4, tx = t & 15;
    float acc[8][8] = {};
    int nsteps = K >> 5;
    for (int s = blockIdx.z; s < nsteps; s += S) {
        int k0 = s << 5;
        // ---- A tile: 128x32, 4 float4 per thread, transposed into As[kk][m]
#pragma unroll
        for (int i = 0; i < 4; ++i) {
            int id = t + i * 256;
            int m  = id >> 3;            // 0..127
            int kc = (id & 7) << 2;      // 0,4,...,28
            float4 av;
            int gm = m0 + m;
            if (gm < M) av = *(const float4*)(A + (size_t)gm * K + k0 + kc);
            else        av = make_float4(0.f, 0.f, 0.f, 0.f);
            As[kc + 0][m] = av.x;
            As[kc + 1][m] = av.y;
            As[kc + 2][m] = av.z;
            As[kc + 3][m] = av.w;
        }
        // ---- B tile
        if (TRANSB) {
#pragma unroll
            for (int i = 0; i < 4; ++i) {
                int id = t + i * 256;
                int n  = id >> 3;
                int kc = (id & 7) << 2;
                float4 bv;
                int gn = n0 + n;
                if (gn < N) bv = *(const float4*)(B + (size_t)gn * ldb + k0 + kc);
                else        bv = make_float4(0.f, 0.f, 0.f, 0.f);
                Bs[kc + 0][n] = bv.x;
                Bs[kc + 1][n] = bv.y;
                Bs[kc + 2][n] = bv.z;
                Bs[kc + 3][n] = bv.w;
            }
        } else {
#pragma unroll
            for (int i = 0; i < 4; ++i) {
                int id = t + i * 256;
                int kk = id >> 5;            // 0..31
                int nc = (id & 31) << 2;     // 0..124
                float4 bv = *(const float4*)(B + (size_t)(k0 + kk) * ldb + n0 + nc);
                *(float4*)&Bs[kk][nc] = bv;
            }
        }
        __syncthreads();
#pragma unroll 8
        for (int kk = 0; kk < 32; ++kk) {
            float4 a0 = *(const float4*)&As[kk][ty * 8];
            float4 a1 = *(const float4*)&As[kk][ty * 8 + 4];
            float4 b0 = *(const float4*)&Bs[kk][tx * 8];
            float4 b1 = *(const float4*)&Bs[kk][tx * 8 + 4];
            float ar[8] = {a0.x, a0.y, a0.z, a0.w, a1.x, a1.y, a1.z, a1.w};
            float br[8] = {b0.x, b0.y, b0.z, b0.w, b1.x, b1.y, b1.z, b1.w};
#pragma unroll
            for (int i2 = 0; i2 < 8; ++i2)
#pragma unroll
                for (int j2 = 0; j2 < 8; ++j2) acc[i2][j2] += ar[i2] * br[j2];
        }
        __syncthreads();
    }
#pragma unroll
    for (int i2 = 0; i2 < 8; ++i2) {
        int m = m0 + ty * 8 + i2;
        if (m < M) {
#pragma unroll
            for (int j2 = 0; j2 < 8; ++j2) {
                int n = n0 + tx * 8 + j2;
                if (n < N) unsafeAtomicAdd(&C[(size_t)m * ldc + n], acc[i2][j2]);
            }
        }
    }
}

// ---------------- epilogue: h = relu(h + bias) in place (N=1024 rows) --------
__global__ __launch_bounds__(256) void ep_bias_relu(float* __restrict__ h,
                                                    const float* __restrict__ bias) {
    int s = blockIdx.x;
    int t = threadIdx.x;
    float4* p = (float4*)(h + (size_t)s * NH) + t;
    float4 v  = *p;
    float4 b  = *((const float4*)bias + t);
    v.x = fmaxf(v.x + b.x, 0.0f);
    v.y = fmaxf(v.y + b.y, 0.0f);
    v.z = fmaxf(v.z + b.z, 0.0f);
    v.w = fmaxf(v.w + b.w, 0.0f);
    *p = v;
}

// ---------------- epilogue: aff = exp(-dot * invn_i * invn_j) in place -------
__global__ __launch_bounds__(256) void aff_finish(float* __restrict__ aff,
                                                  const float* __restrict__ invn) {
    int i = blockIdx.x;
    int t = threadIdx.x;
    float im = invn[i];
    for (int j = t; j < NSEG; j += 256) {
        size_t idx = (size_t)i * NSEG + j;
        aff[idx] = expf(-aff[idx] * im * invn[j]);
    }
}

// ---------------- row inverse norms of feat ----------------------------------
__global__ __launch_bounds__(256) void norm_kernel(const float* __restrict__ feat,
                                                   float* __restrict__ invn) {
    int s = blockIdx.x;
    int t = threadIdx.x;
    const float* r = feat + (size_t)s * CF;
    float acc = 0.0f;
    for (int c = t * 4; c < CF; c += 1024) {
        float4 v = *(const float4*)(r + c);
        acc += v.x * v.x + v.y * v.y + v.z * v.z + v.w * v.w;
    }
    for (int off = 32; off; off >>= 1) acc += __shfl_down(acc, off);
    __shared__ float w[4];
    if ((t & 63) == 0) w[t >> 6] = acc;
    __syncthreads();
    if (t == 0) {
        float tot = w[0] + w[1] + w[2] + w[3];
        invn[s] = 1.0f / sqrtf(fmaxf(tot, 1e-30f));
    }
}

// ---------------- fused layer3 + classifier + softmax ------------------------
__global__ __launch_bounds__(256) void head_kernel(const float* __restrict__ h2,
                                                   const float* __restrict__ W3,
                                                   const float* __restrict__ b3,
                                                   const float* __restrict__ Wc,
                                                   const float* __restrict__ bc,
                                                   float* __restrict__ out) {
    int s = blockIdx.x;
    int t = threadIdx.x;
    int d = t & 31, p = t >> 5;   // 8 k-chunks of 128
    const float* row = h2 + (size_t)s * NH;
    float acc = 0.0f;
    int kend = p * 128 + 128;
    for (int k = p * 128; k < kend; ++k) acc += row[k] * W3[k * 32 + d];
    __shared__ float red[8][32];
    __shared__ float h3[32];
    red[p][d] = acc;
    __syncthreads();
    if (t < 32) {
        float v = 0.0f;
#pragma unroll
        for (int q = 0; q < 8; ++q) v += red[q][t];
        v += b3[t];
        h3[t] = fmaxf(v, 0.0f);
    }
    __syncthreads();
    if (t == 0) {
        float l0 = bc[0], l1 = bc[1];
#pragma unroll
        for (int dd = 0; dd < 32; ++dd) {
            l0 += h3[dd] * Wc[2 * dd];
            l1 += h3[dd] * Wc[2 * dd + 1];
        }
        float m  = fmaxf(l0, l1);
        float e0 = expf(l0 - m), e1 = expf(l1 - m);
        float inv = 1.0f / (e0 + e1);
        out[2 * s]     = e0 * inv;
        out[2 * s + 1] = e1 * inv;
    }
}

// ---------------- masked row max/argmax -> new labels ------------------------
__global__ void newlab_kernel(const float* __restrict__ aff,
                              const int* __restrict__ lab,
                              float* __restrict__ out) {
    int i    = blockIdx.x;
    int lane = threadIdx.x;
    float best = -INFINITY;
    int   bidx = 0x7FFFFFFF;
    for (int j = lane; j < NSEG; j += 64) {
        if (lab[j] != 0) {
            float v = aff[(size_t)i * NSEG + j];
            if (v > best) { best = v; bidx = j; }
        }
    }
    for (int off = 32; off; off >>= 1) {
        float ov = __shfl_down(best, off);
        int   oi = __shfl_down(bidx, off);
        if (ov > best || (ov == best && oi < bidx)) { best = ov; bidx = oi; }
    }
    if (lane == 0) {
        int li = lab[i];
        int nl = li;
        if (li == 0 && best >= 0.7f && bidx != 0x7FFFFFFF) nl = lab[bidx];
        out[880 + i] = (float)nl;
    }
}

extern "C" void kernel_launch(void* const* d_in, const int* in_sizes, int n_in,
                              void* d_out, int out_size, void* d_ws, size_t ws_size,
                              hipStream_t stream) {
    const float* fm = (const float*)d_in[0];
    const int*   sp = (const int*)d_in[1];
    const int*   y  = (const int*)d_in[2];
    const float* W1 = (const float*)d_in[3];
    const float* b1 = (const float*)d_in[4];
    const float* W2 = (const float*)d_in[5];
    const float* b2 = (const float*)d_in[6];
    const float* W3 = (const float*)d_in[7];
    const float* b3 = (const float*)d_in[8];
    const float* Wc = (const float*)d_in[9];
    const float* bc = (const float*)d_in[10];
    float* out = (float*)d_out;
    float* ws  = (float*)d_ws;

    float* hist = ws + OFF_HIST;
    float* feat = ws + OFF_FEAT;
    float* h1   = ws + OFF_H1;
    float* h2   = ws + OFF_H2;
    float* aff  = ws + OFF_AFF;
    float* invn = ws + OFF_INVN;
    int*   lab  = (int*)(ws + OFF_LAB);

    hipMemsetAsync(hist, 0, NSEG * 3 * sizeof(float), stream);
    // h1 and h2 are contiguous; zero both in one call. aff zeroed separately.
    hipMemsetAsync(h1, 0, 2 * NSEG * NH * sizeof(float), stream);
    hipMemsetAsync(aff, 0, NSEG * NSEG * sizeof(float), stream);

    hist_kernel<<<64, 256, 0, stream>>>(sp, y, hist);
    segsum_kernel<<<CF, 256, 0, stream>>>(fm, sp, hist, feat);
    lab_kernel<<<2, 256, 0, stream>>>(hist, lab);

    // h1 = relu(feat @ W1 + b1):  M=440, N=1024, K=2112; 8x4 tiles x 16 splits
    gemm_splitk<0><<<dim3(8, 4, 16), 256, 0, stream>>>(feat, W1, h1,
                                                       NSEG, NH, CF, NH, NH);
    ep_bias_relu<<<NSEG, 256, 0, stream>>>(h1, b1);

    // h2 = relu(h1 @ W2 + b2):  M=440, N=1024, K=1024
    gemm_splitk<0><<<dim3(8, 4, 16), 256, 0, stream>>>(h1, W2, h2,
                                                       NSEG, NH, NH, NH, NH);
    ep_bias_relu<<<NSEG, 256, 0, stream>>>(h2, b2);

    head_kernel<<<NSEG, 256, 0, stream>>>(h2, W3, b3, Wc, bc, out);

    norm_kernel<<<NSEG, 256, 0, stream>>>(feat, invn);

    // aff_raw = feat @ feat^T:  M=N=440, K=2112; 4x4 tiles x 32 splits
    gemm_splitk<1><<<dim3(4, 4, 32), 256, 0, stream>>>(feat, feat, aff,
                                                       NSEG, NSEG, CF, CF, NSEG);
    aff_finish<<<NSEG, 256, 0, stream>>>(aff, invn);

    newlab_kernel<<<NSEG, 64, 0, stream>>>(aff, lab, out);
}